// Round 2
// baseline (890.408 us; speedup 1.0000x reference)
//
#include <hip/hip_runtime.h>
#include <math.h>

#define N_NODES 20000
#define N_EDGES 160000
// ws layout (bytes). Total ~46.5 MB.
static const size_t OFF_G   = 0;                                   // g_ws [64][N_EDGES] f32 (k-major)
static const size_t OFF_SH  = OFF_G  + (size_t)64 * N_EDGES * 4;   // sh_ws [8][N_EDGES] f32
static const size_t OFF_W4R = OFF_SH + (size_t)8  * N_EDGES * 4;   // W4R [4096][16] f32 (12 used + 4 pad)
static const size_t OFF_W1T = OFF_W4R + (size_t)4096 * 16 * 4;     // w1T [64][16]
static const size_t OFF_W2T = OFF_W1T + (size_t)64 * 16 * 4;       // w2T [64][64]
static const size_t OFF_W3T = OFF_W2T + (size_t)64 * 64 * 4;       // w3T [64][64]
static const size_t OFF_AI  = OFF_W3T + (size_t)64 * 64 * 4;       // AiTable [10][8]
static const size_t OFF_CNT = OFF_AI + 512;                        // cnt [N_NODES] f32

// prep_kernel index-space bounds
#define PREP_W4R_END 49152                     // 4096*12
#define PREP_W1T_END (PREP_W4R_END + 1024)     // 64*16
#define PREP_W2T_END (PREP_W1T_END + 4096)     // 64*64
#define PREP_W3T_END (PREP_W2T_END + 4096)     // 64*64  -> total 58368

__device__ __forceinline__ float silu_f(float x) {
    return x / (1.0f + __expf(-x));
}

// ---------------- K1: node-type MLP table (10 types, Ai = 8 floats each) -------------
__global__ void ai_table_kernel(const float* __restrict__ emb,
                                const float* __restrict__ w1, const float* __restrict__ b1,
                                const float* __restrict__ w2, const float* __restrict__ b2,
                                const float* __restrict__ w3, const float* __restrict__ b3,
                                float* __restrict__ ai_out) {
    __shared__ float h1[64];
    __shared__ float h2[32];
    int t = blockIdx.x;        // atom type 0..9
    int j = threadIdx.x;       // 0..63
    float acc = b1[j];
    #pragma unroll
    for (int i = 0; i < 16; i++) acc += emb[t * 16 + i] * w1[i * 64 + j];
    h1[j] = silu_f(acc);
    __syncthreads();
    if (j < 32) {
        float a2 = b2[j];
        #pragma unroll
        for (int i = 0; i < 64; i++) a2 += h1[i] * w2[i * 32 + j];
        h2[j] = silu_f(a2);
    }
    __syncthreads();
    if (j < 8) {
        float a3 = b3[j];
        #pragma unroll
        for (int i = 0; i < 32; i++) a3 += h2[i] * w3[i * 8 + j];
        ai_out[t * 8 + j] = a3;   // no activation on final layer
    }
}

// ---------------- K2: weight reorder / transposes ------------------------------------
// W4R[kappa=(k,u,v)][j=(l*4+w)] = fc_w4[k][((l*8+u)*8+v)*4 + w], row padded to 16 floats.
// w1T/w2T/w3T: [out][in] transposes of fc_w1/fc_w2/fc_w3 for scalar-load streaming.
__global__ void prep_kernel(const float* __restrict__ fc_w1, const float* __restrict__ fc_w2,
                            const float* __restrict__ fc_w3, const float* __restrict__ fc_w4,
                            float* __restrict__ w4r, float* __restrict__ w1t,
                            float* __restrict__ w2t, float* __restrict__ w3t) {
    int idx = blockIdx.x * 256 + threadIdx.x;
    if (idx < PREP_W4R_END) {
        int kappa = idx / 12;
        int j = idx - kappa * 12;
        int l = j >> 2, w = j & 3;
        int v = kappa & 7, u = (kappa >> 3) & 7, k = kappa >> 6;
        w4r[kappa * 16 + j] = fc_w4[k * 768 + ((l * 8 + u) * 8 + v) * 4 + w];
    } else if (idx < PREP_W1T_END) {
        int t = idx - PREP_W4R_END; int j = t >> 4, i = t & 15;
        w1t[j * 16 + i] = fc_w1[i * 64 + j];
    } else if (idx < PREP_W2T_END) {
        int t = idx - PREP_W1T_END; int j = t >> 6, i = t & 63;
        w2t[j * 64 + i] = fc_w2[i * 64 + j];
    } else if (idx < PREP_W3T_END) {
        int t = idx - PREP_W2T_END; int j = t >> 6, i = t & 63;
        w3t[j * 64 + i] = fc_w3[i * 64 + j];
    }
}

// ---------------- K3: per-edge geometry + radial MLP, writes g (k-major) + sh --------
__global__ __launch_bounds__(128) void edge_g_kernel(
        const float* __restrict__ pos, const int* __restrict__ batch,
        const int* __restrict__ esrc, const int* __restrict__ edst,
        const float* __restrict__ shifts, const float* __restrict__ cell,
        const float* __restrict__ w1t, const float* __restrict__ w2t,
        const float* __restrict__ w3t,
        float* __restrict__ g_ws, float* __restrict__ sh_ws) {
    __shared__ float hl[64 * 128];          // [j][tid] ping-pong, column-private per thread
    int tid = threadIdx.x;
    int e = blockIdx.x * 128 + tid;
    if (e >= N_EDGES) return;

    int s = esrc[e], d = edst[e];
    int gb = batch[s];
    float t0 = shifts[e * 3 + 0], t1 = shifts[e * 3 + 1], t2 = shifts[e * 3 + 2];
    const float* C = cell + gb * 9;
    float shx = t0 * C[0] + t1 * C[3] + t2 * C[6];
    float shy = t0 * C[1] + t1 * C[4] + t2 * C[7];
    float shz = t0 * C[2] + t1 * C[5] + t2 * C[8];
    float ex = pos[d * 3 + 0] - pos[s * 3 + 0] + shx;
    float ey = pos[d * 3 + 1] - pos[s * 3 + 1] + shy;
    float ez = pos[d * 3 + 2] - pos[s * 3 + 2] + shz;
    float r = sqrtf(ex * ex + ey * ey + ez * ez);
    float inv = 1.0f / fmaxf(r, 1e-9f);
    float x = ex * inv, y = ey * inv, z = ez * inv;

    const float S3  = 1.7320508075688772f;
    const float S15 = 3.8729833462074170f;
    const float S5  = 2.2360679774997896f;
    sh_ws[0 * N_EDGES + e] = S3 * y;
    sh_ws[1 * N_EDGES + e] = S3 * z;
    sh_ws[2 * N_EDGES + e] = S3 * x;
    sh_ws[3 * N_EDGES + e] = S15 * x * y;
    sh_ws[4 * N_EDGES + e] = S15 * y * z;
    sh_ws[5 * N_EDGES + e] = 0.5f * S5 * (3.0f * z * z - 1.0f);
    sh_ws[6 * N_EDGES + e] = S15 * x * z;
    sh_ws[7 * N_EDGES + e] = 0.5f * S15 * (x * x - y * y);

    // radial basis: centers (i+1)*5/17, step 5/17, scale sqrt(16)/1.12
    float rb[16];
    const float step = 5.0f / 17.0f;
    const float istep = 17.0f / 5.0f;
    const float rsc = 4.0f / 1.12f;
    #pragma unroll
    for (int i = 0; i < 16; i++) {
        float dd = (r - (float)(i + 1) * step) * istep;
        rb[i] = __expf(-dd * dd) * rsc;
    }

    // L1: 16 -> 64  (g = silu(rb @ fc_w1 / 4))
    for (int j = 0; j < 64; j++) {
        const float* wr = w1t + j * 16;     // uniform address -> scalar loads
        float a0 = 0, a1 = 0, a2 = 0, a3 = 0;
        #pragma unroll
        for (int i = 0; i < 16; i += 4) {
            a0 += rb[i] * wr[i];     a1 += rb[i + 1] * wr[i + 1];
            a2 += rb[i + 2] * wr[i + 2]; a3 += rb[i + 3] * wr[i + 3];
        }
        hl[j * 128 + tid] = silu_f(((a0 + a1) + (a2 + a3)) * 0.25f);
    }
    float h[64];
    #pragma unroll
    for (int i = 0; i < 64; i++) h[i] = hl[i * 128 + tid];

    // L2: 64 -> 64  (silu(h @ fc_w2 / 8))
    for (int j = 0; j < 64; j++) {
        const float* wr = w2t + j * 64;
        float a0 = 0, a1 = 0, a2 = 0, a3 = 0;
        #pragma unroll
        for (int i = 0; i < 64; i += 4) {
            a0 += h[i] * wr[i];       a1 += h[i + 1] * wr[i + 1];
            a2 += h[i + 2] * wr[i + 2]; a3 += h[i + 3] * wr[i + 3];
        }
        hl[j * 128 + tid] = silu_f(((a0 + a1) + (a2 + a3)) * 0.125f);
    }
    #pragma unroll
    for (int i = 0; i < 64; i++) h[i] = hl[i * 128 + tid];

    // L3: 64 -> 64  (silu(h @ fc_w3 / 8)) -> g, stored k-major for coalesced main-kernel reads
    for (int j = 0; j < 64; j++) {
        const float* wr = w3t + j * 64;
        float a0 = 0, a1 = 0, a2 = 0, a3 = 0;
        #pragma unroll
        for (int i = 0; i < 64; i += 4) {
            a0 += h[i] * wr[i];       a1 += h[i + 1] * wr[i + 1];
            a2 += h[i + 2] * wr[i + 2]; a3 += h[i + 3] * wr[i + 3];
        }
        g_ws[j * N_EDGES + e] = silu_f(((a0 + a1) + (a2 + a3)) * 0.125f);
    }
}

// ---------------- K4: main contraction  S[e,l,w] = (1/64) sum g_k a_u b_v W4 ----------
__global__ __launch_bounds__(256) void main_kernel(
        const int* __restrict__ A, const int* __restrict__ esrc, const int* __restrict__ edst,
        const float* __restrict__ g_ws, const float* __restrict__ sh_ws,
        const float* __restrict__ w4r, const float* __restrict__ ai_tab,
        float* __restrict__ out, float* __restrict__ cnt) {
    int e = blockIdx.x * 256 + threadIdx.x;
    if (e >= N_EDGES) return;
    int s = esrc[e], d = edst[e];
    int ts = A[s], td = A[d];

    float a[8], b[8];
    {
        const float4* ap = (const float4*)(ai_tab + ts * 8);
        float4 x0 = ap[0], x1 = ap[1];
        a[0] = x0.x; a[1] = x0.y; a[2] = x0.z; a[3] = x0.w;
        a[4] = x1.x; a[5] = x1.y; a[6] = x1.z; a[7] = x1.w;
        const float4* bp = (const float4*)(ai_tab + td * 8);
        float4 y0 = bp[0], y1 = bp[1];
        b[0] = y0.x; b[1] = y0.y; b[2] = y0.z; b[3] = y0.w;
        b[4] = y1.x; b[5] = y1.y; b[6] = y1.z; b[7] = y1.w;
    }

    float sv[12];
    #pragma unroll
    for (int i = 0; i < 12; i++) sv[i] = 0.0f;

    for (int k = 0; k < 64; k++) {
        float gk = g_ws[k * N_EDGES + e];       // coalesced
        #pragma unroll
        for (int u = 0; u < 8; u++) {
            float ga = gk * a[u];
            #pragma unroll
            for (int v = 0; v < 8; v++) {
                float f2 = ga * b[v];
                const float* wr = w4r + (((k * 8 + u) * 8 + v) << 4);  // uniform -> scalar loads
                float4 wa = *(const float4*)(wr);
                float4 wb = *(const float4*)(wr + 4);
                float4 wc = *(const float4*)(wr + 8);
                sv[0] += f2 * wa.x; sv[1] += f2 * wa.y; sv[2]  += f2 * wa.z; sv[3]  += f2 * wa.w;
                sv[4] += f2 * wb.x; sv[5] += f2 * wb.y; sv[6]  += f2 * wb.z; sv[7]  += f2 * wb.w;
                sv[8] += f2 * wc.x; sv[9] += f2 * wc.y; sv[10] += f2 * wc.z; sv[11] += f2 * wc.w;
            }
        }
    }

    float shv[8];
    #pragma unroll
    for (int i = 0; i < 8; i++) shv[i] = sh_ws[i * N_EDGES + e];

    const float isc = 1.0f / 64.0f;   // (1/8 from w, 1/8 from einsum/MUL_IN)
    float* o = out + d * 36;
    #pragma unroll
    for (int w = 0; w < 4; w++) atomicAdd(o + w, sv[w] * isc);
    #pragma unroll
    for (int w = 0; w < 4; w++) {
        float sw = sv[4 + w] * isc;
        #pragma unroll
        for (int j = 0; j < 3; j++) atomicAdd(o + 4 + w * 3 + j, sw * shv[j]);
    }
    #pragma unroll
    for (int w = 0; w < 4; w++) {
        float sw = sv[8 + w] * isc;
        #pragma unroll
        for (int j = 0; j < 5; j++) atomicAdd(o + 16 + w * 5 + j, sw * shv[3 + j]);
    }
    atomicAdd(cnt + d, 1.0f);
}

// ---------------- K5: divide by per-node edge count ----------------------------------
__global__ void finalize_kernel(float* __restrict__ out, const float* __restrict__ cnt) {
    int i = blockIdx.x * 256 + threadIdx.x;
    if (i < N_NODES * 36) {
        float c = cnt[i / 36];
        out[i] = out[i] / fmaxf(c, 1.0f);
    }
}

extern "C" void kernel_launch(void* const* d_in, const int* in_sizes, int n_in,
                              void* d_out, int out_size, void* d_ws, size_t ws_size,
                              hipStream_t stream) {
    const float* pos    = (const float*)d_in[0];
    const int*   A      = (const int*)d_in[1];
    const int*   batch  = (const int*)d_in[2];
    const int*   esrc   = (const int*)d_in[3];
    const int*   edst   = (const int*)d_in[4];
    const float* shifts = (const float*)d_in[5];
    const float* cell   = (const float*)d_in[6];
    const float* emb    = (const float*)d_in[7];
    const float* fw1    = (const float*)d_in[8];
    const float* fb1    = (const float*)d_in[9];
    const float* fw2    = (const float*)d_in[10];
    const float* fb2    = (const float*)d_in[11];
    const float* fw3    = (const float*)d_in[12];
    const float* fb3    = (const float*)d_in[13];
    const float* fcw1   = (const float*)d_in[14];
    const float* fcw2   = (const float*)d_in[15];
    const float* fcw3   = (const float*)d_in[16];
    const float* fcw4   = (const float*)d_in[17];
    float* out = (float*)d_out;

    char* ws = (char*)d_ws;
    float* g_ws   = (float*)(ws + OFF_G);
    float* sh_ws  = (float*)(ws + OFF_SH);
    float* w4r    = (float*)(ws + OFF_W4R);
    float* w1t    = (float*)(ws + OFF_W1T);
    float* w2t    = (float*)(ws + OFF_W2T);
    float* w3t    = (float*)(ws + OFF_W3T);
    float* ai_tab = (float*)(ws + OFF_AI);
    float* cnt    = (float*)(ws + OFF_CNT);

    hipMemsetAsync(out, 0, (size_t)N_NODES * 36 * 4, stream);
    hipMemsetAsync(cnt, 0, (size_t)N_NODES * 4, stream);

    ai_table_kernel<<<10, 64, 0, stream>>>(emb, fw1, fb1, fw2, fb2, fw3, fb3, ai_tab);
    prep_kernel<<<(PREP_W3T_END + 255) / 256, 256, 0, stream>>>(fcw1, fcw2, fcw3, fcw4, w4r, w1t, w2t, w3t);
    edge_g_kernel<<<(N_EDGES + 127) / 128, 128, 0, stream>>>(
        pos, batch, esrc, edst, shifts, cell, w1t, w2t, w3t, g_ws, sh_ws);
    main_kernel<<<(N_EDGES + 255) / 256, 256, 0, stream>>>(
        A, esrc, edst, g_ws, sh_ws, w4r, ai_tab, out, cnt);
    finalize_kernel<<<(N_NODES * 36 + 255) / 256, 256, 0, stream>>>(out, cnt);
}